// Round 10
// baseline (364.556 us; speedup 1.0000x reference)
//
#include <hip/hip_runtime.h>
#include <hip/hip_bf16.h>

// MoE SwiGLU FFN, top-2 of 8 experts. N=4096, D_MODEL=2048, D_FF=1408.
// Fast path: pre-convert x -> bf16, weights -> transposed bf16 [n][k] in ws.
// gemm1: 256-row tile, 128 fused gate+up cols, 8 waves, 128KiB dbuf LDS,
//        counted-vmcnt depth-2 pipeline, m201-style 4-phase inner loop
//        ({ds_read subtile -> lgkm(0) -> 16 MFMA -> barrier} per phase).
// gemm2: 128x128 tile, 4 waves, 64KiB dbuf, 2-phase inner loop, ATOMIC-FREE:
//        writes per-slot bf16 rows; combine kernel does the scored top-2 sum.
// Both: XOR bank-swizzle (both-sides via pre-swizzled global source), XCD swizzle.

#define NTOK 4096
#define DMODEL 2048
#define DFF 1408
#define NEXP 8
#define TOPK 2
#define NSLOT (NTOK * TOPK)
#define MAX_TILES 160
#define NTILE_A 40             // NSLOT/256 + NEXP  (gemm1 row tiles)
#define NTILE_B 72             // NSLOT/128 + NEXP  (gemm2 row tiles)
#define NY1 11                 // DFF/128
#define NY2 16                 // DMODEL/128

typedef short bf16x8 __attribute__((ext_vector_type(8)));
typedef float f32x4 __attribute__((ext_vector_type(4)));

#define MFMA16(a, b, c) __builtin_amdgcn_mfma_f32_16x16x32_bf16(a, b, c, 0, 0, 0)

__device__ inline void async16(const void* g, void* l) {
    __builtin_amdgcn_global_load_lds(
        (const __attribute__((address_space(1))) void*)g,
        (__attribute__((address_space(3))) void*)l, 16, 0, 0);
}

// bijective XCD-chunked swizzle (m204)
__device__ inline int xcd_swz(int bid, int nblk) {
    int q = nblk >> 3, r = nblk & 7;
    int x = bid & 7, p = bid >> 3;
    return (x < r ? x * (q + 1) : r * (q + 1) + (x - r) * q) + p;
}

// ---------------- routing ----------------
__global__ __launch_bounds__(256) void route_kernel(
    const int* __restrict__ idx, const float* __restrict__ scores,
    int* __restrict__ metaA, int* __restrict__ metaB,
    int* __restrict__ slot_token, float* __restrict__ slot_score,
    int* __restrict__ tok_slot, int bmA, int bmB)
{
    __shared__ int counts[NEXP];
    __shared__ int cursor[NEXP];
    int t = threadIdx.x;
    if (t < NEXP) counts[t] = 0;
    __syncthreads();
    for (int i = t; i < NSLOT; i += 256) atomicAdd(&counts[idx[i]], 1);
    __syncthreads();
    if (t == 0) {
        int off = 0, nt = 0;
        for (int e = 0; e < NEXP; e++) {
            cursor[e] = off;
            int c = counts[e];
            for (int s = 0; s < c && nt < MAX_TILES; s += bmA) {
                metaA[1 + nt * 3 + 0] = e;
                metaA[1 + nt * 3 + 1] = off + s;
                metaA[1 + nt * 3 + 2] = min(bmA, c - s);
                nt++;
            }
            off += c;
        }
        metaA[0] = nt;
        off = 0; nt = 0;
        for (int e = 0; e < NEXP; e++) {
            int c = counts[e];
            for (int s = 0; s < c && nt < MAX_TILES; s += bmB) {
                metaB[1 + nt * 3 + 0] = e;
                metaB[1 + nt * 3 + 1] = off + s;
                metaB[1 + nt * 3 + 2] = min(bmB, c - s);
                nt++;
            }
            off += c;
        }
        metaB[0] = nt;
    }
    __syncthreads();
    for (int i = t; i < NSLOT; i += 256) {
        int e = idx[i];
        int pos = atomicAdd(&cursor[e], 1);
        slot_token[pos] = i / TOPK;
        slot_score[pos] = scores[i];
        tok_slot[i] = pos;                 // token i/TOPK, choice i%TOPK -> slot
    }
}

// ---------------- pre-pass: x fp32 -> bf16 ----------------
__global__ __launch_bounds__(256) void convert_x(
    const float* __restrict__ x, __hip_bfloat16* __restrict__ xb)
{
    int i = blockIdx.x * 256 + threadIdx.x;
    float4 v = reinterpret_cast<const float4*>(x)[i];
    __hip_bfloat16 o[4] = {(__hip_bfloat16)v.x, (__hip_bfloat16)v.y,
                           (__hip_bfloat16)v.z, (__hip_bfloat16)v.w};
    *reinterpret_cast<uint2*>(&xb[(size_t)i * 4]) = *reinterpret_cast<uint2*>(o);
}

// ---------------- pre-pass: per-expert fp32 [R][C] -> bf16 [C][R] ----------------
__global__ __launch_bounds__(256) void transpose_convert(
    const float* __restrict__ in, __hip_bfloat16* __restrict__ out, int R, int C)
{
    __shared__ __hip_bfloat16 t[64][72];
    const size_t base = (size_t)blockIdx.z * R * C;
    const int c0 = blockIdx.x * 64, r0 = blockIdx.y * 64;
    const int tid = threadIdx.x;
    const int rl = tid >> 4, c4 = (tid & 15) * 4;
    #pragma unroll
    for (int j = 0; j < 4; j++) {
        int r = rl + j * 16;
        float4 v = *reinterpret_cast<const float4*>(&in[base + (size_t)(r0 + r) * C + c0 + c4]);
        t[c4 + 0][r] = (__hip_bfloat16)v.x;
        t[c4 + 1][r] = (__hip_bfloat16)v.y;
        t[c4 + 2][r] = (__hip_bfloat16)v.z;
        t[c4 + 3][r] = (__hip_bfloat16)v.w;
    }
    __syncthreads();
    const int nl = tid >> 3, k8 = (tid & 7) * 8;
    #pragma unroll
    for (int j = 0; j < 2; j++) {
        int n = nl + j * 32;
        const uint* p = reinterpret_cast<const uint*>(&t[n][k8]);
        uint4 o = {p[0], p[1], p[2], p[3]};
        *reinterpret_cast<uint4*>(&out[base + (size_t)(c0 + n) * R + r0 + k8]) = o;
    }
}

// ---------------- combine: out[tok] = s0*so[slot0] + s1*so[slot1] ----------------
__global__ __launch_bounds__(256) void combine_kernel(
    const __hip_bfloat16* __restrict__ so, const int* __restrict__ tok_slot,
    const float* __restrict__ slot_score, float* __restrict__ out)
{
    const int tok = blockIdx.x;
    const int c = threadIdx.x * 8;
    const int s0 = tok_slot[tok * 2 + 0], s1 = tok_slot[tok * 2 + 1];
    const float w0 = slot_score[s0], w1 = slot_score[s1];
    bf16x8 v0 = *reinterpret_cast<const bf16x8*>(&so[(size_t)s0 * DMODEL + c]);
    bf16x8 v1 = *reinterpret_cast<const bf16x8*>(&so[(size_t)s1 * DMODEL + c]);
    float res[8];
    #pragma unroll
    for (int j = 0; j < 8; j++) {
        float f0 = __uint_as_float(((uint)(unsigned short)v0[j]) << 16);
        float f1 = __uint_as_float(((uint)(unsigned short)v1[j]) << 16);
        res[j] = w0 * f0 + w1 * f1;
    }
    float4* dst = reinterpret_cast<float4*>(&out[(size_t)tok * DMODEL + c]);
    dst[0] = *reinterpret_cast<float4*>(&res[0]);
    dst[1] = *reinterpret_cast<float4*>(&res[4]);
}

// ---------------- GEMM1: h = silu(x@Wg)*(x@Wu). BM=256, 128 fused cols, 8 waves ----------------
__global__ __launch_bounds__(512, 2) void moe_gemm1_fast(
    const __hip_bfloat16* __restrict__ xb,
    const __hip_bfloat16* __restrict__ WgT, const __hip_bfloat16* __restrict__ WuT,
    const int* __restrict__ meta, const int* __restrict__ slot_token,
    __hip_bfloat16* __restrict__ h)
{
    const int swz = xcd_swz(blockIdx.x, NTILE_A * NY1);
    const int tile = swz / NY1, yb = swz % NY1;
    if (tile >= meta[0]) return;
    const int e = meta[1 + tile * 3], slot0 = meta[2 + tile * 3], rows = meta[3 + tile * 3];
    const int n0 = yb * 128;

    __shared__ __hip_bfloat16 As[2][256][64];    // 64 KB
    __shared__ __hip_bfloat16 Bgs[2][128][64];   // 32 KB
    __shared__ __hip_bfloat16 Bus[2][128][64];   // 32 KB

    const int tid = threadIdx.x, lane = tid & 63, w = tid >> 6;
    const int wm = w >> 2, wn = w & 3, l15 = lane & 15, lg = lane >> 4;
    const int swb = l15 & 7;

    uint aoff[4], boff[2];
    #pragma unroll
    for (int i = 0; i < 4; i++) {
        int chunk = tid + i * 512;
        int r = chunk >> 3;
        int rc = r < rows ? r : rows - 1;
        int slot8 = (chunk & 7) ^ (r & 7);
        aoff[i] = (uint)(slot_token[slot0 + rc] * (DMODEL * 2) + slot8 * 16);
    }
    #pragma unroll
    for (int i = 0; i < 2; i++) {
        int chunk = tid + i * 512;
        int n = chunk >> 3;
        int slot8 = (chunk & 7) ^ (n & 7);
        boff[i] = (uint)((n0 + n) * (DMODEL * 2) + slot8 * 16);
    }
    const char* xbp = (const char*)xb;
    const char* wgp = (const char*)(WgT + (size_t)e * DFF * DMODEL);
    const char* wup = (const char*)(WuT + (size_t)e * DFF * DMODEL);

    f32x4 ag[8][2] = {};
    f32x4 au[8][2] = {};

    auto stage = [&](int kt, int buf) {          // 8 loads per thread
        const int kb = kt * 128;
        char* ab = (char*)As[buf]  + w * 1024;
        char* gb = (char*)Bgs[buf] + w * 1024;
        char* ub = (char*)Bus[buf] + w * 1024;
        #pragma unroll
        for (int i = 0; i < 4; i++) async16(xbp + aoff[i] + kb, ab + i * 8192);
        #pragma unroll
        for (int i = 0; i < 2; i++) {
            async16(wgp + boff[i] + kb, gb + i * 8192);
            async16(wup + boff[i] + kb, ub + i * 8192);
        }
    };

    constexpr int NT = DMODEL / 64;              // 32
    stage(0, 0);
    stage(1, 1);

    for (int kt = 0; kt < NT; ++kt) {
        const int cur = kt & 1;
        if (kt < NT - 1) asm volatile("s_waitcnt vmcnt(8)" ::: "memory");
        else             asm volatile("s_waitcnt vmcnt(0)" ::: "memory");
        __builtin_amdgcn_s_barrier();            // tile kt staged (all waves)

        bf16x8 bgk[2], buk[2];
        #pragma unroll
        for (int p = 0; p < 4; p++) {            // phase = (kk, mh): 16 MFMA each
            const int kk = p >> 1, mh = p & 1;
            const int cb = ((kk * 4 + lg) ^ swb) * 16;
            bf16x8 a[4];
            #pragma unroll
            for (int mi = 0; mi < 4; mi++)
                a[mi] = *(const bf16x8*)((const char*)&As[cur][wm * 128 + (mh * 4 + mi) * 16 + l15][0] + cb);
            if (mh == 0) {
                #pragma unroll
                for (int nf = 0; nf < 2; nf++) {
                    bgk[nf] = *(const bf16x8*)((const char*)&Bgs[cur][wn * 32 + nf * 16 + l15][0] + cb);
                    buk[nf] = *(const bf16x8*)((const char*)&Bus[cur][wn * 32 + nf * 16 + l15][0] + cb);
                }
            }
            asm volatile("s_waitcnt lgkmcnt(0)" ::: "memory");
            __builtin_amdgcn_sched_barrier(0);
            __builtin_amdgcn_s_setprio(1);
            #pragma unroll
            for (int mi = 0; mi < 4; mi++) {
                const int mf = mh * 4 + mi;
                #pragma unroll
                for (int nf = 0; nf < 2; nf++) {
                    ag[mf][nf] = MFMA16(a[mi], bgk[nf], ag[mf][nf]);
                    au[mf][nf] = MFMA16(a[mi], buk[nf], au[mf][nf]);
                }
            }
            __builtin_amdgcn_s_setprio(0);
            __builtin_amdgcn_s_barrier();        // phase sync; last one = reads-done
        }
        if (kt + 2 < NT) stage(kt + 2, cur);     // overwrite freed buffer
    }

    #pragma unroll
    for (int mf = 0; mf < 8; mf++) {
        #pragma unroll
        for (int j = 0; j < 4; j++) {
            int r = wm * 128 + mf * 16 + lg * 4 + j;
            if (r < rows) {
                size_t hrow = (size_t)(slot0 + r) * DFF + n0 + wn * 32;
                #pragma unroll
                for (int nf = 0; nf < 2; nf++) {
                    float g = ag[mf][nf][j], u = au[mf][nf][j];
                    float hv = g / (1.0f + __expf(-g)) * u;
                    h[hrow + nf * 16 + l15] = (__hip_bfloat16)hv;
                }
            }
        }
    }
}

// ---------------- GEMM2: so[slot] = h@Wd (bf16, atomic-free). BM=128, BN=128, 4 waves ----------------
__global__ __launch_bounds__(256, 2) void moe_gemm2_fast(
    const __hip_bfloat16* __restrict__ h, const __hip_bfloat16* __restrict__ WdT,
    const int* __restrict__ meta, __hip_bfloat16* __restrict__ so)
{
    const int swz = xcd_swz(blockIdx.x, NTILE_B * NY2);
    const int tile = swz / NY2, yb = swz % NY2;
    if (tile >= meta[0]) return;
    const int e = meta[1 + tile * 3], slot0 = meta[2 + tile * 3], rows = meta[3 + tile * 3];
    const int n0 = yb * 128;

    __shared__ __hip_bfloat16 Ah[2][128][64];   // 32 KB
    __shared__ __hip_bfloat16 Bd[2][128][64];   // 32 KB

    const int tid = threadIdx.x, lane = tid & 63, w = tid >> 6;
    const int wm = w >> 1, wn = w & 1, l15 = lane & 15, lg = lane >> 4;
    const int swb = l15 & 7;

    uint aoff[4], boff[4];
    #pragma unroll
    for (int i = 0; i < 4; i++) {
        int chunk = tid + i * 256;
        int r = chunk >> 3;
        int rc = r < rows ? r : rows - 1;
        int slot8 = (chunk & 7) ^ (r & 7);
        aoff[i] = (uint)((slot0 + rc) * (DFF * 2) + slot8 * 16);
        boff[i] = (uint)((n0 + r) * (DFF * 2) + slot8 * 16);
    }
    const char* hp  = (const char*)h;
    const char* wdp = (const char*)(WdT + (size_t)e * DMODEL * DFF);

    f32x4 acc[4][4] = {};

    auto stage = [&](int kt, int buf) {        // 8 loads per thread
        const int kb = kt * 128;
        char* ab = (char*)Ah[buf] + w * 1024;
        char* bb = (char*)Bd[buf] + w * 1024;
        #pragma unroll
        for (int i = 0; i < 4; i++) {
            async16(hp  + aoff[i] + kb, ab + i * 4096);
            async16(wdp + boff[i] + kb, bb + i * 4096);
        }
    };

    constexpr int NT = DFF / 64;               // 22
    stage(0, 0);
    stage(1, 1);

    for (int kt = 0; kt < NT; ++kt) {
        const int cur = kt & 1;
        if (kt < NT - 1) asm volatile("s_waitcnt vmcnt(8)" ::: "memory");
        else             asm volatile("s_waitcnt vmcnt(0)" ::: "memory");
        __builtin_amdgcn_s_barrier();

        #pragma unroll
        for (int p = 0; p < 2; p++) {           // phase = kk: 16 MFMA each
            const int cb = ((p * 4 + lg) ^ swb) * 16;
            bf16x8 a[4], b[4];
            #pragma unroll
            for (int mf = 0; mf < 4; mf++) {
                a[mf] = *(const bf16x8*)((const char*)&Ah[cur][wm * 64 + mf * 16 + l15][0] + cb);
                b[mf] = *(const bf16x8*)((const char*)&Bd[cur][wn * 64 + mf * 16 + l15][0] + cb);
            }
            asm volatile("s_waitcnt lgkmcnt(0)" ::: "memory");
            __builtin_amdgcn_sched_barrier(0);
            __builtin_amdgcn_s_setprio(1);
            #pragma unroll
            for (int mf = 0; mf < 4; mf++)
                #pragma unroll
                for (int nf = 0; nf < 4; nf++)
                    acc[mf][nf] = MFMA16(a[mf], b[nf], acc[mf][nf]);
            __builtin_amdgcn_s_setprio(0);
            __builtin_amdgcn_s_barrier();
        }
        if (kt + 2 < NT) stage(kt + 2, cur);
    }

    #pragma unroll
    for (int mf = 0; mf < 4; mf++) {
        #pragma unroll
        for (int j = 0; j < 4; j++) {
            int r = wm * 64 + mf * 16 + lg * 4 + j;
            if (r < rows) {
                size_t orow = (size_t)(slot0 + r) * DMODEL + n0 + wn * 64;
                #pragma unroll
                for (int nf = 0; nf < 4; nf++)
                    so[orow + nf * 16 + l15] = (__hip_bfloat16)acc[mf][nf][j];
            }
        }
    }
}

// ================= fallback (round-2, known-good) =================
__global__ __launch_bounds__(256) void moe_gemm1(
    const float* __restrict__ x, const float* __restrict__ Wg, const float* __restrict__ Wu,
    const int* __restrict__ meta, const int* __restrict__ slot_token,
    __hip_bfloat16* __restrict__ h)
{
    int tile = blockIdx.x;
    if (tile >= meta[0]) return;
    const int e = meta[1 + tile * 3], slot0 = meta[2 + tile * 3], rows = meta[3 + tile * 3];
    const int n0 = blockIdx.y * 64;
    __shared__ __hip_bfloat16 As[64][72];
    __shared__ __hip_bfloat16 Bgs[64][72];
    __shared__ __hip_bfloat16 Bus[64][72];
    const int tid = threadIdx.x, lane = tid & 63, w = tid >> 6;
    const int wm = w >> 1, wn = w & 1, l15 = lane & 15, lg = lane >> 4;
    const float* __restrict__ WgE = Wg + (size_t)e * DMODEL * DFF;
    const float* __restrict__ WuE = Wu + (size_t)e * DMODEL * DFF;
    f32x4 acc_g[2][2] = {};
    f32x4 acc_u[2][2] = {};
    for (int k0 = 0; k0 < DMODEL; k0 += 64) {
        __syncthreads();
        #pragma unroll
        for (int j = 0; j < 4; j++) {
            int linear = tid + j * 256;
            int r = linear >> 4, c4 = (linear & 15) * 4;
            int tok = (r < rows) ? slot_token[slot0 + r] : 0;
            float4 v = *reinterpret_cast<const float4*>(&x[(size_t)tok * DMODEL + k0 + c4]);
            As[r][c4 + 0] = (__hip_bfloat16)v.x; As[r][c4 + 1] = (__hip_bfloat16)v.y;
            As[r][c4 + 2] = (__hip_bfloat16)v.z; As[r][c4 + 3] = (__hip_bfloat16)v.w;
        }
        #pragma unroll
        for (int j = 0; j < 4; j++) {
            int linear = tid + j * 256;
            int k = linear >> 4, n4 = (linear & 15) * 4;
            float4 vg = *reinterpret_cast<const float4*>(&WgE[(size_t)(k0 + k) * DFF + n0 + n4]);
            Bgs[n4 + 0][k] = (__hip_bfloat16)vg.x; Bgs[n4 + 1][k] = (__hip_bfloat16)vg.y;
            Bgs[n4 + 2][k] = (__hip_bfloat16)vg.z; Bgs[n4 + 3][k] = (__hip_bfloat16)vg.w;
            float4 vu = *reinterpret_cast<const float4*>(&WuE[(size_t)(k0 + k) * DFF + n0 + n4]);
            Bus[n4 + 0][k] = (__hip_bfloat16)vu.x; Bus[n4 + 1][k] = (__hip_bfloat16)vu.y;
            Bus[n4 + 2][k] = (__hip_bfloat16)vu.z; Bus[n4 + 3][k] = (__hip_bfloat16)vu.w;
        }
        __syncthreads();
        #pragma unroll
        for (int kk = 0; kk < 2; kk++) {
            bf16x8 a[2], bg[2], bu[2];
            #pragma unroll
            for (int mf = 0; mf < 2; mf++)
                a[mf] = *reinterpret_cast<const bf16x8*>(&As[wm * 32 + mf * 16 + l15][kk * 32 + lg * 8]);
            #pragma unroll
            for (int nf = 0; nf < 2; nf++) {
                bg[nf] = *reinterpret_cast<const bf16x8*>(&Bgs[wn * 32 + nf * 16 + l15][kk * 32 + lg * 8]);
                bu[nf] = *reinterpret_cast<const bf16x8*>(&Bus[wn * 32 + nf * 16 + l15][kk * 32 + lg * 8]);
            }
            #pragma unroll
            for (int mf = 0; mf < 2; mf++)
                #pragma unroll
                for (int nf = 0; nf < 2; nf++) {
                    acc_g[mf][nf] = MFMA16(a[mf], bg[nf], acc_g[mf][nf]);
                    acc_u[mf][nf] = MFMA16(a[mf], bu[nf], acc_u[mf][nf]);
                }
        }
    }
    #pragma unroll
    for (int mf = 0; mf < 2; mf++)
        #pragma unroll
        for (int nf = 0; nf < 2; nf++)
            #pragma unroll
            for (int j = 0; j < 4; j++) {
                int r = wm * 32 + mf * 16 + lg * 4 + j;
                int c = wn * 32 + nf * 16 + l15;
                if (r < rows) {
                    float g = acc_g[mf][nf][j], u = acc_u[mf][nf][j];
                    h[(size_t)(slot0 + r) * DFF + n0 + c] = (__hip_bfloat16)(g / (1.0f + __expf(-g)) * u);
                }
            }
}

__global__ __launch_bounds__(256) void moe_gemm2(
    const __hip_bfloat16* __restrict__ h, const float* __restrict__ Wd,
    const int* __restrict__ meta, const int* __restrict__ slot_token,
    const float* __restrict__ slot_score, float* __restrict__ out)
{
    int tile = blockIdx.x;
    if (tile >= meta[0]) return;
    const int e = meta[1 + tile * 3], slot0 = meta[2 + tile * 3], rows = meta[3 + tile * 3];
    const int n0 = blockIdx.y * 64;
    __shared__ __hip_bfloat16 As[64][72];
    __shared__ __hip_bfloat16 Bs[64][72];
    const int tid = threadIdx.x, lane = tid & 63, w = tid >> 6;
    const int wm = w >> 1, wn = w & 1, l15 = lane & 15, lg = lane >> 4;
    const float* __restrict__ WdE = Wd + (size_t)e * DFF * DMODEL;
    f32x4 acc[2][2] = {};
    for (int k0 = 0; k0 < DFF; k0 += 64) {
        __syncthreads();
        #pragma unroll
        for (int j = 0; j < 2; j++) {
            int linear = tid + j * 256;
            int r = linear >> 3, c8 = (linear & 7) * 8;
            bf16x8 v = *reinterpret_cast<const bf16x8*>(&h[(size_t)(slot0 + r) * DFF + k0 + c8]);
            *reinterpret_cast<bf16x8*>(&As[r][c8]) = v;
        }
        #pragma unroll
        for (int j = 0; j < 4; j++) {
            int linear = tid + j * 256;
            int k = linear >> 4, n4 = (linear & 15) * 4;
            float4 v = *reinterpret_cast<const float4*>(&WdE[(size_t)(k0 + k) * DMODEL + n0 + n4]);
            Bs[n4 + 0][k] = (__hip_bfloat16)v.x; Bs[n4 + 1][k] = (__hip_bfloat16)v.y;
            Bs[n4 + 2][k] = (__hip_bfloat16)v.z; Bs[n4 + 3][k] = (__hip_bfloat16)v.w;
        }
        __syncthreads();
        #pragma unroll
        for (int kk = 0; kk < 2; kk++) {
            bf16x8 a[2], b[2];
            #pragma unroll
            for (int mf = 0; mf < 2; mf++)
                a[mf] = *reinterpret_cast<const bf16x8*>(&As[wm * 32 + mf * 16 + l15][kk * 32 + lg * 8]);
            #pragma unroll
            for (int nf = 0; nf < 2; nf++)
                b[nf] = *reinterpret_cast<const bf16x8*>(&Bs[wn * 32 + nf * 16 + l15][kk * 32 + lg * 8]);
            #pragma unroll
            for (int mf = 0; mf < 2; mf++)
                #pragma unroll
                for (int nf = 0; nf < 2; nf++)
                    acc[mf][nf] = MFMA16(a[mf], b[nf], acc[mf][nf]);
        }
    }
    #pragma unroll
    for (int mf = 0; mf < 2; mf++)
        #pragma unroll
        for (int nf = 0; nf < 2; nf++)
            #pragma unroll
            for (int j = 0; j < 4; j++) {
                int r = wm * 32 + mf * 16 + lg * 4 + j;
                int c = wn * 32 + nf * 16 + l15;
                if (r < rows) {
                    int slot = slot0 + r;
                    atomicAdd(&out[(size_t)slot_token[slot] * DMODEL + n0 + c],
                              acc[mf][nf][j] * slot_score[slot]);
                }
            }
}

extern "C" void kernel_launch(void* const* d_in, const int* in_sizes, int n_in,
                              void* d_out, int out_size, void* d_ws, size_t ws_size,
                              hipStream_t stream) {
    const float* x      = (const float*)d_in[0];
    const int*   idx    = (const int*)d_in[1];
    const float* scores = (const float*)d_in[2];
    const float* Wg     = (const float*)d_in[3];
    const float* Wu     = (const float*)d_in[4];
    const float* Wd     = (const float*)d_in[5];
    float* out = (float*)d_out;

    char* ws = (char*)d_ws;
    int*   metaA      = (int*)ws;                       // 256-row tiles (gemm1)
    int*   metaB      = (int*)(ws + 4096);              // 128-row tiles (gemm2)
    int*   slot_token = (int*)(ws + 8192);              // 8448 ints
    float* slot_score = (float*)(ws + 8192 + 40960);    // 8448 floats
    int*   tok_slot   = (int*)(ws + 8192 + 81920);      // 8192 ints

    const size_t XB_OFF = (size_t)1 << 20;
    const size_t HB_OFF = (size_t)20 << 20;
    const size_t WG_OFF = (size_t)44 << 20;   // WgT during gemm1; slot_out after
    const size_t WU_OFF = (size_t)92 << 20;
    const size_t WD_OFF = (size_t)140 << 20;
    const size_t NEED   = (size_t)187 << 20;
    const bool fast = ws_size >= NEED;

    route_kernel<<<1, 256, 0, stream>>>(idx, scores, metaA, metaB, slot_token, slot_score,
                                        tok_slot, fast ? 256 : 64, fast ? 128 : 64);

    if (fast) {
        __hip_bfloat16* xb  = (__hip_bfloat16*)(ws + XB_OFF);
        __hip_bfloat16* hb  = (__hip_bfloat16*)(ws + HB_OFF);
        __hip_bfloat16* WgT = (__hip_bfloat16*)(ws + WG_OFF);
        __hip_bfloat16* WuT = (__hip_bfloat16*)(ws + WU_OFF);
        __hip_bfloat16* WdT = (__hip_bfloat16*)(ws + WD_OFF);
        __hip_bfloat16* sot = (__hip_bfloat16*)(ws + WG_OFF);  // reuse WgT after gemm1

        // Wd first so gemm1's inputs (WgT/WuT/xb) are most-recent in L3.
        dim3 td(DMODEL / 64, DFF / 64, NEXP);
        transpose_convert<<<td, 256, 0, stream>>>(Wd, WdT, DFF, DMODEL);
        dim3 tg(DFF / 64, DMODEL / 64, NEXP);
        transpose_convert<<<tg, 256, 0, stream>>>(Wg, WgT, DMODEL, DFF);
        transpose_convert<<<tg, 256, 0, stream>>>(Wu, WuT, DMODEL, DFF);
        convert_x<<<(NTOK * DMODEL / 4) / 256, 256, 0, stream>>>(x, xb);

        moe_gemm1_fast<<<NTILE_A * NY1, 512, 0, stream>>>(xb, WgT, WuT, metaA, slot_token, hb);
        moe_gemm2_fast<<<NTILE_B * NY2, 256, 0, stream>>>(hb, WdT, metaB, sot);
        combine_kernel<<<NTOK, 256, 0, stream>>>(sot, tok_slot, slot_score, out);
    } else {
        __hip_bfloat16* hb = (__hip_bfloat16*)(ws + HB_OFF);
        hipMemsetAsync(d_out, 0, (size_t)NTOK * DMODEL * sizeof(float), stream);
        dim3 g1(NSLOT / 64 + NEXP, DFF / 64);
        moe_gemm1<<<g1, 256, 0, stream>>>(x, Wg, Wu, metaA, slot_token, hb);
        dim3 g2(NSLOT / 64 + NEXP, DMODEL / 64);
        moe_gemm2<<<g2, 256, 0, stream>>>(hb, Wd, metaB, slot_token, slot_score, out);
    }
}

// Round 12
// 342.479 us; speedup vs baseline: 1.0645x; 1.0645x over previous
//
#include <hip/hip_runtime.h>
#include <hip/hip_bf16.h>

// MoE SwiGLU FFN, top-2 of 8 experts. N=4096, D_MODEL=2048, D_FF=1408.
// gemm1: 256-row tile, 128 fused gate+up cols, 8 waves, 128KiB dbuf LDS.
//        PROVEN round-7/8 hazard skeleton (bulk 8-load stage, vmcnt(8)+barrier
//        at tile top, stage(kt+2) after all-reads barrier) with an m201-style
//        4-quadrant phase loop inside: per phase {ds_reads -> s_barrier ->
//        lgkmcnt(0) -> 16 MFMA -> s_barrier}.
// gemm2: 128x128, 4 waves, proven bulk loop, atomic-free bf16 epilogue;
//        combine kernel does the scored top-2 sum (no memset, no atomics).
// Both: XOR bank-swizzle via pre-swizzled global source, XCD swizzle.

#define NTOK 4096
#define DMODEL 2048
#define DFF 1408
#define NEXP 8
#define TOPK 2
#define NSLOT (NTOK * TOPK)
#define MAX_TILES 160
#define NTILE_A 40             // NSLOT/256 + NEXP  (gemm1 row tiles)
#define NTILE_B 72             // NSLOT/128 + NEXP  (gemm2 row tiles)
#define NY1 11                 // DFF/128
#define NY2 16                 // DMODEL/128

typedef short bf16x8 __attribute__((ext_vector_type(8)));
typedef float f32x4 __attribute__((ext_vector_type(4)));

#define MFMA16(a, b, c) __builtin_amdgcn_mfma_f32_16x16x32_bf16(a, b, c, 0, 0, 0)

__device__ inline void async16(const void* g, void* l) {
    __builtin_amdgcn_global_load_lds(
        (const __attribute__((address_space(1))) void*)g,
        (__attribute__((address_space(3))) void*)l, 16, 0, 0);
}

// bijective XCD-chunked swizzle (m204)
__device__ inline int xcd_swz(int bid, int nblk) {
    int q = nblk >> 3, r = nblk & 7;
    int x = bid & 7, p = bid >> 3;
    return (x < r ? x * (q + 1) : r * (q + 1) + (x - r) * q) + p;
}

// ---------------- routing ----------------
__global__ __launch_bounds__(256) void route_kernel(
    const int* __restrict__ idx, const float* __restrict__ scores,
    int* __restrict__ metaA, int* __restrict__ metaB,
    int* __restrict__ slot_token, float* __restrict__ slot_score,
    int* __restrict__ tok_slot, int bmA, int bmB)
{
    __shared__ int counts[NEXP];
    __shared__ int cursor[NEXP];
    int t = threadIdx.x;
    if (t < NEXP) counts[t] = 0;
    __syncthreads();
    for (int i = t; i < NSLOT; i += 256) atomicAdd(&counts[idx[i]], 1);
    __syncthreads();
    if (t == 0) {
        int off = 0, nt = 0;
        for (int e = 0; e < NEXP; e++) {
            cursor[e] = off;
            int c = counts[e];
            for (int s = 0; s < c && nt < MAX_TILES; s += bmA) {
                metaA[1 + nt * 3 + 0] = e;
                metaA[1 + nt * 3 + 1] = off + s;
                metaA[1 + nt * 3 + 2] = min(bmA, c - s);
                nt++;
            }
            off += c;
        }
        metaA[0] = nt;
        off = 0; nt = 0;
        for (int e = 0; e < NEXP; e++) {
            int c = counts[e];
            for (int s = 0; s < c && nt < MAX_TILES; s += bmB) {
                metaB[1 + nt * 3 + 0] = e;
                metaB[1 + nt * 3 + 1] = off + s;
                metaB[1 + nt * 3 + 2] = min(bmB, c - s);
                nt++;
            }
            off += c;
        }
        metaB[0] = nt;
    }
    __syncthreads();
    for (int i = t; i < NSLOT; i += 256) {
        int e = idx[i];
        int pos = atomicAdd(&cursor[e], 1);
        slot_token[pos] = i / TOPK;
        slot_score[pos] = scores[i];
        tok_slot[i] = pos;
    }
}

// ---------------- pre-pass: x fp32 -> bf16 ----------------
__global__ __launch_bounds__(256) void convert_x(
    const float* __restrict__ x, __hip_bfloat16* __restrict__ xb)
{
    int i = blockIdx.x * 256 + threadIdx.x;
    float4 v = reinterpret_cast<const float4*>(x)[i];
    __hip_bfloat16 o[4] = {(__hip_bfloat16)v.x, (__hip_bfloat16)v.y,
                           (__hip_bfloat16)v.z, (__hip_bfloat16)v.w};
    *reinterpret_cast<uint2*>(&xb[(size_t)i * 4]) = *reinterpret_cast<uint2*>(o);
}

// ---------------- pre-pass: per-expert fp32 [R][C] -> bf16 [C][R] ----------------
__global__ __launch_bounds__(256) void transpose_convert(
    const float* __restrict__ in, __hip_bfloat16* __restrict__ out, int R, int C)
{
    __shared__ __hip_bfloat16 t[64][72];
    const size_t base = (size_t)blockIdx.z * R * C;
    const int c0 = blockIdx.x * 64, r0 = blockIdx.y * 64;
    const int tid = threadIdx.x;
    const int rl = tid >> 4, c4 = (tid & 15) * 4;
    #pragma unroll
    for (int j = 0; j < 4; j++) {
        int r = rl + j * 16;
        float4 v = *reinterpret_cast<const float4*>(&in[base + (size_t)(r0 + r) * C + c0 + c4]);
        t[c4 + 0][r] = (__hip_bfloat16)v.x;
        t[c4 + 1][r] = (__hip_bfloat16)v.y;
        t[c4 + 2][r] = (__hip_bfloat16)v.z;
        t[c4 + 3][r] = (__hip_bfloat16)v.w;
    }
    __syncthreads();
    const int nl = tid >> 3, k8 = (tid & 7) * 8;
    #pragma unroll
    for (int j = 0; j < 2; j++) {
        int n = nl + j * 32;
        const uint* p = reinterpret_cast<const uint*>(&t[n][k8]);
        uint4 o = {p[0], p[1], p[2], p[3]};
        *reinterpret_cast<uint4*>(&out[base + (size_t)(c0 + n) * R + r0 + k8]) = o;
    }
}

// ---------------- combine: out[tok] = s0*so[slot0] + s1*so[slot1] ----------------
__global__ __launch_bounds__(256) void combine_kernel(
    const __hip_bfloat16* __restrict__ so, const int* __restrict__ tok_slot,
    const float* __restrict__ slot_score, float* __restrict__ out)
{
    const int tok = blockIdx.x;
    const int c = threadIdx.x * 8;
    const int s0 = tok_slot[tok * 2 + 0], s1 = tok_slot[tok * 2 + 1];
    const float w0 = slot_score[s0], w1 = slot_score[s1];
    bf16x8 v0 = *reinterpret_cast<const bf16x8*>(&so[(size_t)s0 * DMODEL + c]);
    bf16x8 v1 = *reinterpret_cast<const bf16x8*>(&so[(size_t)s1 * DMODEL + c]);
    float res[8];
    #pragma unroll
    for (int j = 0; j < 8; j++) {
        float f0 = __uint_as_float(((uint)(unsigned short)v0[j]) << 16);
        float f1 = __uint_as_float(((uint)(unsigned short)v1[j]) << 16);
        res[j] = w0 * f0 + w1 * f1;
    }
    float4* dst = reinterpret_cast<float4*>(&out[(size_t)tok * DMODEL + c]);
    dst[0] = *reinterpret_cast<float4*>(&res[0]);
    dst[1] = *reinterpret_cast<float4*>(&res[4]);
}

// ---------------- GEMM1: h = silu(x@Wg)*(x@Wu). BM=256, 128 fused cols, 8 waves ----------------
__global__ __launch_bounds__(512, 2) void moe_gemm1_fast(
    const __hip_bfloat16* __restrict__ xb,
    const __hip_bfloat16* __restrict__ WgT, const __hip_bfloat16* __restrict__ WuT,
    const int* __restrict__ meta, const int* __restrict__ slot_token,
    __hip_bfloat16* __restrict__ h)
{
    const int swz = xcd_swz(blockIdx.x, NTILE_A * NY1);
    const int tile = swz / NY1, yb = swz % NY1;
    if (tile >= meta[0]) return;
    const int e = meta[1 + tile * 3], slot0 = meta[2 + tile * 3], rows = meta[3 + tile * 3];
    const int n0 = yb * 128;

    __shared__ __hip_bfloat16 As[2][256][64];    // 64 KB
    __shared__ __hip_bfloat16 Bgs[2][128][64];   // 32 KB
    __shared__ __hip_bfloat16 Bus[2][128][64];   // 32 KB

    const int tid = threadIdx.x, lane = tid & 63, w = tid >> 6;
    const int wm = w >> 2, wn = w & 3, l15 = lane & 15, lg = lane >> 4;
    const int swb = l15 & 7;

    // Pre-swizzled 32-bit source offsets (round-8 proven chunk layout).
    uint aoff[4], boff[2];
    #pragma unroll
    for (int i = 0; i < 4; i++) {
        int chunk = tid + i * 512;               // [0,2048): row = chunk>>3
        int r = chunk >> 3;
        int rc = r < rows ? r : rows - 1;
        int slot8 = (chunk & 7) ^ (r & 7);
        aoff[i] = (uint)(slot_token[slot0 + rc] * (DMODEL * 2) + slot8 * 16);
    }
    #pragma unroll
    for (int i = 0; i < 2; i++) {
        int chunk = tid + i * 512;               // [0,1024): n = chunk>>3
        int n = chunk >> 3;
        int slot8 = (chunk & 7) ^ (n & 7);
        boff[i] = (uint)((n0 + n) * (DMODEL * 2) + slot8 * 16);
    }
    const char* xbp = (const char*)xb;
    const char* wgp = (const char*)(WgT + (size_t)e * DFF * DMODEL);
    const char* wup = (const char*)(WuT + (size_t)e * DFF * DMODEL);

    f32x4 ag[8][2] = {};
    f32x4 au[8][2] = {};

    auto stage = [&](int kt, int buf) {          // 8 loads per thread (bulk, proven)
        const int kb = kt * 128;
        char* ab = (char*)As[buf]  + w * 1024;
        char* gb = (char*)Bgs[buf] + w * 1024;
        char* ub = (char*)Bus[buf] + w * 1024;
        #pragma unroll
        for (int i = 0; i < 4; i++) async16(xbp + aoff[i] + kb, ab + i * 8192);
        #pragma unroll
        for (int i = 0; i < 2; i++) {
            async16(wgp + boff[i] + kb, gb + i * 8192);
            async16(wup + boff[i] + kb, ub + i * 8192);
        }
    };

    constexpr int NT = DMODEL / 64;              // 32
    stage(0, 0);
    stage(1, 1);

    for (int kt = 0; kt < NT; ++kt) {
        const int cur = kt & 1;
        if (kt < NT - 1) asm volatile("s_waitcnt vmcnt(8)" ::: "memory");
        else             asm volatile("s_waitcnt vmcnt(0)" ::: "memory");
        __builtin_amdgcn_s_barrier();            // tile kt fully staged (all waves)

        bf16x8 a[4][2], bg[2][2], bu[2][2];

        // ---- P1: read A(mh0) + Bg; MFMA ag[0..3] ----
        #pragma unroll
        for (int kk = 0; kk < 2; kk++) {
            const int cb = ((kk * 4 + lg) ^ swb) * 16;
            #pragma unroll
            for (int mi = 0; mi < 4; mi++)
                a[mi][kk] = *(const bf16x8*)((const char*)&As[cur][wm * 128 + mi * 16 + l15][0] + cb);
            #pragma unroll
            for (int nf = 0; nf < 2; nf++)
                bg[nf][kk] = *(const bf16x8*)((const char*)&Bgs[cur][wn * 32 + nf * 16 + l15][0] + cb);
        }
        __builtin_amdgcn_s_barrier();
        asm volatile("s_waitcnt lgkmcnt(0)" ::: "memory");
        __builtin_amdgcn_sched_barrier(0);
        __builtin_amdgcn_s_setprio(1);
        #pragma unroll
        for (int kk = 0; kk < 2; kk++)
            #pragma unroll
            for (int mi = 0; mi < 4; mi++)
                #pragma unroll
                for (int nf = 0; nf < 2; nf++)
                    ag[mi][nf] = MFMA16(a[mi][kk], bg[nf][kk], ag[mi][nf]);
        __builtin_amdgcn_s_setprio(0);
        __builtin_amdgcn_s_barrier();

        // ---- P2: read Bu; MFMA au[0..3] ----
        #pragma unroll
        for (int kk = 0; kk < 2; kk++) {
            const int cb = ((kk * 4 + lg) ^ swb) * 16;
            #pragma unroll
            for (int nf = 0; nf < 2; nf++)
                bu[nf][kk] = *(const bf16x8*)((const char*)&Bus[cur][wn * 32 + nf * 16 + l15][0] + cb);
        }
        __builtin_amdgcn_s_barrier();
        asm volatile("s_waitcnt lgkmcnt(0)" ::: "memory");
        __builtin_amdgcn_sched_barrier(0);
        __builtin_amdgcn_s_setprio(1);
        #pragma unroll
        for (int kk = 0; kk < 2; kk++)
            #pragma unroll
            for (int mi = 0; mi < 4; mi++)
                #pragma unroll
                for (int nf = 0; nf < 2; nf++)
                    au[mi][nf] = MFMA16(a[mi][kk], bu[nf][kk], au[mi][nf]);
        __builtin_amdgcn_s_setprio(0);
        __builtin_amdgcn_s_barrier();

        // ---- P3: read A(mh1); MFMA ag[4..7] ----
        #pragma unroll
        for (int kk = 0; kk < 2; kk++) {
            const int cb = ((kk * 4 + lg) ^ swb) * 16;
            #pragma unroll
            for (int mi = 0; mi < 4; mi++)
                a[mi][kk] = *(const bf16x8*)((const char*)&As[cur][wm * 128 + 64 + mi * 16 + l15][0] + cb);
        }
        __builtin_amdgcn_s_barrier();
        asm volatile("s_waitcnt lgkmcnt(0)" ::: "memory");
        __builtin_amdgcn_sched_barrier(0);
        __builtin_amdgcn_s_setprio(1);
        #pragma unroll
        for (int kk = 0; kk < 2; kk++)
            #pragma unroll
            for (int mi = 0; mi < 4; mi++)
                #pragma unroll
                for (int nf = 0; nf < 2; nf++)
                    ag[4 + mi][nf] = MFMA16(a[mi][kk], bg[nf][kk], ag[4 + mi][nf]);
        __builtin_amdgcn_s_setprio(0);
        __builtin_amdgcn_s_barrier();
        // After this barrier every wave has passed lgkmcnt(0) covering ALL its
        // reads of buf[cur] (P4 reads nothing) -> safe to overwrite buf[cur].

        // ---- P4: stage(kt+2) into freed buffer; MFMA au[4..7] ----
        if (kt + 2 < NT) stage(kt + 2, cur);
        __builtin_amdgcn_s_setprio(1);
        #pragma unroll
        for (int kk = 0; kk < 2; kk++)
            #pragma unroll
            for (int mi = 0; mi < 4; mi++)
                #pragma unroll
                for (int nf = 0; nf < 2; nf++)
                    au[4 + mi][nf] = MFMA16(a[mi][kk], bu[nf][kk], au[4 + mi][nf]);
        __builtin_amdgcn_s_setprio(0);
    }

    #pragma unroll
    for (int mf = 0; mf < 8; mf++) {
        #pragma unroll
        for (int j = 0; j < 4; j++) {
            int r = wm * 128 + ((mf >> 2) * 64) + (mf & 3) * 16 + lg * 4 + j;
            if (r < rows) {
                size_t hrow = (size_t)(slot0 + r) * DFF + n0 + wn * 32;
                #pragma unroll
                for (int nf = 0; nf < 2; nf++) {
                    float g = ag[mf][nf][j], u = au[mf][nf][j];
                    float hv = g / (1.0f + __expf(-g)) * u;
                    h[hrow + nf * 16 + l15] = (__hip_bfloat16)hv;
                }
            }
        }
    }
}

// ---------------- GEMM2: so[slot] = h@Wd (bf16, atomic-free). BM=128, BN=128 ----------------
__global__ __launch_bounds__(256, 2) void moe_gemm2_fast(
    const __hip_bfloat16* __restrict__ h, const __hip_bfloat16* __restrict__ WdT,
    const int* __restrict__ meta, __hip_bfloat16* __restrict__ so)
{
    const int swz = xcd_swz(blockIdx.x, NTILE_B * NY2);
    const int tile = swz / NY2, yb = swz % NY2;
    if (tile >= meta[0]) return;
    const int e = meta[1 + tile * 3], slot0 = meta[2 + tile * 3], rows = meta[3 + tile * 3];
    const int n0 = yb * 128;

    __shared__ __hip_bfloat16 Ah[2][128][64];   // 32 KB
    __shared__ __hip_bfloat16 Bd[2][128][64];   // 32 KB

    const int tid = threadIdx.x, lane = tid & 63, w = tid >> 6;
    const int wm = w >> 1, wn = w & 1, l15 = lane & 15, lg = lane >> 4;
    const int swb = l15 & 7;

    uint aoff[4], boff[4];
    #pragma unroll
    for (int i = 0; i < 4; i++) {
        int chunk = tid + i * 256;
        int r = chunk >> 3;
        int rc = r < rows ? r : rows - 1;
        int slot8 = (chunk & 7) ^ (r & 7);
        aoff[i] = (uint)((slot0 + rc) * (DFF * 2) + slot8 * 16);
        boff[i] = (uint)((n0 + r) * (DFF * 2) + slot8 * 16);
    }
    const char* hp  = (const char*)h;
    const char* wdp = (const char*)(WdT + (size_t)e * DMODEL * DFF);

    f32x4 acc[4][4] = {};

    auto stage = [&](int kt, int buf) {        // 8 loads per thread
        const int kb = kt * 128;
        char* ab = (char*)Ah[buf] + w * 1024;
        char* bb = (char*)Bd[buf] + w * 1024;
        #pragma unroll
        for (int i = 0; i < 4; i++) {
            async16(hp  + aoff[i] + kb, ab + i * 4096);
            async16(wdp + boff[i] + kb, bb + i * 4096);
        }
    };

    constexpr int NT = DFF / 64;               // 22
    stage(0, 0);
    stage(1, 1);

    for (int kt = 0; kt < NT; ++kt) {
        const int cur = kt & 1;
        if (kt < NT - 1) asm volatile("s_waitcnt vmcnt(8)" ::: "memory");
        else             asm volatile("s_waitcnt vmcnt(0)" ::: "memory");
        __builtin_amdgcn_s_barrier();

        bf16x8 a[2][4], b[2][4];
        #pragma unroll
        for (int kk = 0; kk < 2; kk++) {
            const int cb = ((kk * 4 + lg) ^ swb) * 16;
            #pragma unroll
            for (int mf = 0; mf < 4; mf++) {
                a[kk][mf] = *(const bf16x8*)((const char*)&Ah[cur][wm * 64 + mf * 16 + l15][0] + cb);
                b[kk][mf] = *(const bf16x8*)((const char*)&Bd[cur][wn * 64 + mf * 16 + l15][0] + cb);
            }
        }
        asm volatile("s_waitcnt lgkmcnt(0)" ::: "memory");
        __builtin_amdgcn_sched_barrier(0);
        __builtin_amdgcn_s_barrier();
        if (kt + 2 < NT) stage(kt + 2, cur);

        __builtin_amdgcn_s_setprio(1);
        #pragma unroll
        for (int kk = 0; kk < 2; kk++)
            #pragma unroll
            for (int mf = 0; mf < 4; mf++)
                #pragma unroll
                for (int nf = 0; nf < 4; nf++)
                    acc[mf][nf] = MFMA16(a[kk][mf], b[kk][nf], acc[mf][nf]);
        __builtin_amdgcn_s_setprio(0);
    }

    #pragma unroll
    for (int mf = 0; mf < 4; mf++) {
        #pragma unroll
        for (int j = 0; j < 4; j++) {
            int r = wm * 64 + mf * 16 + lg * 4 + j;
            if (r < rows) {
                size_t orow = (size_t)(slot0 + r) * DMODEL + n0 + wn * 64;
                #pragma unroll
                for (int nf = 0; nf < 4; nf++)
                    so[orow + nf * 16 + l15] = (__hip_bfloat16)acc[mf][nf][j];
            }
        }
    }
}

// ================= fallback (round-2, known-good) =================
__global__ __launch_bounds__(256) void moe_gemm1(
    const float* __restrict__ x, const float* __restrict__ Wg, const float* __restrict__ Wu,
    const int* __restrict__ meta, const int* __restrict__ slot_token,
    __hip_bfloat16* __restrict__ h)
{
    int tile = blockIdx.x;
    if (tile >= meta[0]) return;
    const int e = meta[1 + tile * 3], slot0 = meta[2 + tile * 3], rows = meta[3 + tile * 3];
    const int n0 = blockIdx.y * 64;
    __shared__ __hip_bfloat16 As[64][72];
    __shared__ __hip_bfloat16 Bgs[64][72];
    __shared__ __hip_bfloat16 Bus[64][72];
    const int tid = threadIdx.x, lane = tid & 63, w = tid >> 6;
    const int wm = w >> 1, wn = w & 1, l15 = lane & 15, lg = lane >> 4;
    const float* __restrict__ WgE = Wg + (size_t)e * DMODEL * DFF;
    const float* __restrict__ WuE = Wu + (size_t)e * DMODEL * DFF;
    f32x4 acc_g[2][2] = {};
    f32x4 acc_u[2][2] = {};
    for (int k0 = 0; k0 < DMODEL; k0 += 64) {
        __syncthreads();
        #pragma unroll
        for (int j = 0; j < 4; j++) {
            int linear = tid + j * 256;
            int r = linear >> 4, c4 = (linear & 15) * 4;
            int tok = (r < rows) ? slot_token[slot0 + r] : 0;
            float4 v = *reinterpret_cast<const float4*>(&x[(size_t)tok * DMODEL + k0 + c4]);
            As[r][c4 + 0] = (__hip_bfloat16)v.x; As[r][c4 + 1] = (__hip_bfloat16)v.y;
            As[r][c4 + 2] = (__hip_bfloat16)v.z; As[r][c4 + 3] = (__hip_bfloat16)v.w;
        }
        #pragma unroll
        for (int j = 0; j < 4; j++) {
            int linear = tid + j * 256;
            int k = linear >> 4, n4 = (linear & 15) * 4;
            float4 vg = *reinterpret_cast<const float4*>(&WgE[(size_t)(k0 + k) * DFF + n0 + n4]);
            Bgs[n4 + 0][k] = (__hip_bfloat16)vg.x; Bgs[n4 + 1][k] = (__hip_bfloat16)vg.y;
            Bgs[n4 + 2][k] = (__hip_bfloat16)vg.z; Bgs[n4 + 3][k] = (__hip_bfloat16)vg.w;
            float4 vu = *reinterpret_cast<const float4*>(&WuE[(size_t)(k0 + k) * DFF + n0 + n4]);
            Bus[n4 + 0][k] = (__hip_bfloat16)vu.x; Bus[n4 + 1][k] = (__hip_bfloat16)vu.y;
            Bus[n4 + 2][k] = (__hip_bfloat16)vu.z; Bus[n4 + 3][k] = (__hip_bfloat16)vu.w;
        }
        __syncthreads();
        #pragma unroll
        for (int kk = 0; kk < 2; kk++) {
            bf16x8 a[2], bg[2], bu[2];
            #pragma unroll
            for (int mf = 0; mf < 2; mf++)
                a[mf] = *reinterpret_cast<const bf16x8*>(&As[wm * 32 + mf * 16 + l15][kk * 32 + lg * 8]);
            #pragma unroll
            for (int nf = 0; nf < 2; nf++) {
                bg[nf] = *reinterpret_cast<const bf16x8*>(&Bgs[wn * 32 + nf * 16 + l15][kk * 32 + lg * 8]);
                bu[nf] = *reinterpret_cast<const bf16x8*>(&Bus[wn * 32 + nf * 16 + l15][kk * 32 + lg * 8]);
            }
            #pragma unroll
            for (int mf = 0; mf < 2; mf++)
                #pragma unroll
                for (int nf = 0; nf < 2; nf++) {
                    acc_g[mf][nf] = MFMA16(a[mf], bg[nf], acc_g[mf][nf]);
                    acc_u[mf][nf] = MFMA16(a[mf], bu[nf], acc_u[mf][nf]);
                }
        }
    }
    #pragma unroll
    for (int mf = 0; mf < 2; mf++)
        #pragma unroll
        for (int nf = 0; nf < 2; nf++)
            #pragma unroll
            for (int j = 0; j < 4; j++) {
                int r = wm * 32 + mf * 16 + lg * 4 + j;
                int c = wn * 32 + nf * 16 + l15;
                if (r < rows) {
                    float g = acc_g[mf][nf][j], u = acc_u[mf][nf][j];
                    h[(size_t)(slot0 + r) * DFF + n0 + c] = (__hip_bfloat16)(g / (1.0f + __expf(-g)) * u);
                }
            }
}

__global__ __launch_bounds__(256) void moe_gemm2(
    const __hip_bfloat16* __restrict__ h, const float* __restrict__ Wd,
    const int* __restrict__ meta, const int* __restrict__ slot_token,
    const float* __restrict__ slot_score, float* __restrict__ out)
{
    int tile = blockIdx.x;
    if (tile >= meta[0]) return;
    const int e = meta[1 + tile * 3], slot0 = meta[2 + tile * 3], rows = meta[3 + tile * 3];
    const int n0 = blockIdx.y * 64;
    __shared__ __hip_bfloat16 As[64][72];
    __shared__ __hip_bfloat16 Bs[64][72];
    const int tid = threadIdx.x, lane = tid & 63, w = tid >> 6;
    const int wm = w >> 1, wn = w & 1, l15 = lane & 15, lg = lane >> 4;
    const float* __restrict__ WdE = Wd + (size_t)e * DFF * DMODEL;
    f32x4 acc[2][2] = {};
    for (int k0 = 0; k0 < DFF; k0 += 64) {
        __syncthreads();
        #pragma unroll
        for (int j = 0; j < 2; j++) {
            int linear = tid + j * 256;
            int r = linear >> 3, c8 = (linear & 7) * 8;
            bf16x8 v = *reinterpret_cast<const bf16x8*>(&h[(size_t)(slot0 + r) * DFF + k0 + c8]);
            *reinterpret_cast<bf16x8*>(&As[r][c8]) = v;
        }
        #pragma unroll
        for (int j = 0; j < 4; j++) {
            int linear = tid + j * 256;
            int k = linear >> 4, n4 = (linear & 15) * 4;
            float4 v = *reinterpret_cast<const float4*>(&WdE[(size_t)(k0 + k) * DMODEL + n0 + n4]);
            Bs[n4 + 0][k] = (__hip_bfloat16)v.x; Bs[n4 + 1][k] = (__hip_bfloat16)v.y;
            Bs[n4 + 2][k] = (__hip_bfloat16)v.z; Bs[n4 + 3][k] = (__hip_bfloat16)v.w;
        }
        __syncthreads();
        #pragma unroll
        for (int kk = 0; kk < 2; kk++) {
            bf16x8 a[2], b[2];
            #pragma unroll
            for (int mf = 0; mf < 2; mf++)
                a[mf] = *reinterpret_cast<const bf16x8*>(&As[wm * 32 + mf * 16 + l15][kk * 32 + lg * 8]);
            #pragma unroll
            for (int nf = 0; nf < 2; nf++)
                b[nf] = *reinterpret_cast<const bf16x8*>(&Bs[wn * 32 + nf * 16 + l15][kk * 32 + lg * 8]);
            #pragma unroll
            for (int mf = 0; mf < 2; mf++)
                #pragma unroll
                for (int nf = 0; nf < 2; nf++)
                    acc[mf][nf] = MFMA16(a[mf], b[nf], acc[mf][nf]);
        }
    }
    #pragma unroll
    for (int mf = 0; mf < 2; mf++)
        #pragma unroll
        for (int nf = 0; nf < 2; nf++)
            #pragma unroll
            for (int j = 0; j < 4; j++) {
                int r = wm * 32 + mf * 16 + lg * 4 + j;
                int c = wn * 32 + nf * 16 + l15;
                if (r < rows) {
                    int slot = slot0 + r;
                    atomicAdd(&out[(size_t)slot_token[slot] * DMODEL + n0 + c],
                              acc[mf][nf][j] * slot_score[slot]);
                }
            }
}

extern "C" void kernel_launch(void* const* d_in, const int* in_sizes, int n_in,
                              void* d_out, int out_size, void* d_ws, size_t ws_size,
                              hipStream_t stream) {
    const float* x      = (const float*)d_in[0];
    const int*   idx    = (const int*)d_in[1];
    const float* scores = (const float*)d_in[2];
    const float* Wg     = (const float*)d_in[3];
    const float* Wu     = (const float*)d_in[4];
    const float* Wd     = (const float*)d_in[5];
    float* out = (float*)d_out;

    char* ws = (char*)d_ws;
    int*   metaA      = (int*)ws;
    int*   metaB      = (int*)(ws + 4096);
    int*   slot_token = (int*)(ws + 8192);
    float* slot_score = (float*)(ws + 8192 + 40960);
    int*   tok_slot   = (int*)(ws + 8192 + 81920);

    const size_t XB_OFF = (size_t)1 << 20;
    const size_t HB_OFF = (size_t)20 << 20;
    const size_t WG_OFF = (size_t)44 << 20;   // WgT during gemm1; slot_out after
    const size_t WU_OFF = (size_t)92 << 20;
    const size_t WD_OFF = (size_t)140 << 20;
    const size_t NEED   = (size_t)187 << 20;
    const bool fast = ws_size >= NEED;

    route_kernel<<<1, 256, 0, stream>>>(idx, scores, metaA, metaB, slot_token, slot_score,
                                        tok_slot, fast ? 256 : 64, fast ? 128 : 64);

    if (fast) {
        __hip_bfloat16* xb  = (__hip_bfloat16*)(ws + XB_OFF);
        __hip_bfloat16* hb  = (__hip_bfloat16*)(ws + HB_OFF);
        __hip_bfloat16* WgT = (__hip_bfloat16*)(ws + WG_OFF);
        __hip_bfloat16* WuT = (__hip_bfloat16*)(ws + WU_OFF);
        __hip_bfloat16* WdT = (__hip_bfloat16*)(ws + WD_OFF);
        __hip_bfloat16* sot = (__hip_bfloat16*)(ws + WG_OFF);  // reuse WgT after gemm1

        dim3 td(DMODEL / 64, DFF / 64, NEXP);
        transpose_convert<<<td, 256, 0, stream>>>(Wd, WdT, DFF, DMODEL);
        dim3 tg(DFF / 64, DMODEL / 64, NEXP);
        transpose_convert<<<tg, 256, 0, stream>>>(Wg, WgT, DMODEL, DFF);
        transpose_convert<<<tg, 256, 0, stream>>>(Wu, WuT, DMODEL, DFF);
        convert_x<<<(NTOK * DMODEL / 4) / 256, 256, 0, stream>>>(x, xb);

        moe_gemm1_fast<<<NTILE_A * NY1, 512, 0, stream>>>(xb, WgT, WuT, metaA, slot_token, hb);
        moe_gemm2_fast<<<NTILE_B * NY2, 256, 0, stream>>>(hb, WdT, metaB, sot);
        combine_kernel<<<NTOK, 256, 0, stream>>>(sot, tok_slot, slot_score, out);
    } else {
        __hip_bfloat16* hb = (__hip_bfloat16*)(ws + HB_OFF);
        hipMemsetAsync(d_out, 0, (size_t)NTOK * DMODEL * sizeof(float), stream);
        dim3 g1(NSLOT / 64 + NEXP, DFF / 64);
        moe_gemm1<<<g1, 256, 0, stream>>>(x, Wg, Wu, metaA, slot_token, hb);
        dim3 g2(NSLOT / 64 + NEXP, DMODEL / 64);
        moe_gemm2<<<g2, 256, 0, stream>>>(hb, Wd, metaB, slot_token, slot_score, out);
    }
}

// Round 13
// 323.744 us; speedup vs baseline: 1.1261x; 1.0579x over previous
//
#include <hip/hip_runtime.h>
#include <hip/hip_bf16.h>

// MoE SwiGLU FFN, top-2 of 8 experts. N=4096, D_MODEL=2048, D_FF=1408.
// gemm1: 256-row tile, 128 fused gate+up cols, 8 waves, 128KiB dbuf LDS,
//        ROUND-8 PROVEN bulk loop: stage 8 loads/thread, vmcnt(8)+barrier at
//        tile top, all ds_reads -> lgkm(0) -> barrier -> stage(kt+2) -> 64 MFMA.
// gemm2: 128x128, 4 waves, proven bulk loop, atomic-free bf16 epilogue;
//        combine kernel does the scored top-2 sum (no memset, no atomics).
// Both: XOR bank-swizzle via pre-swizzled global source, XCD swizzle.

#define NTOK 4096
#define DMODEL 2048
#define DFF 1408
#define NEXP 8
#define TOPK 2
#define NSLOT (NTOK * TOPK)
#define MAX_TILES 160
#define NTILE_A 40             // NSLOT/256 + NEXP  (gemm1 row tiles)
#define NTILE_B 72             // NSLOT/128 + NEXP  (gemm2 row tiles)
#define NY1 11                 // DFF/128
#define NY2 16                 // DMODEL/128

typedef short bf16x8 __attribute__((ext_vector_type(8)));
typedef float f32x4 __attribute__((ext_vector_type(4)));

#define MFMA16(a, b, c) __builtin_amdgcn_mfma_f32_16x16x32_bf16(a, b, c, 0, 0, 0)

__device__ inline void async16(const void* g, void* l) {
    __builtin_amdgcn_global_load_lds(
        (const __attribute__((address_space(1))) void*)g,
        (__attribute__((address_space(3))) void*)l, 16, 0, 0);
}

// bijective XCD-chunked swizzle (m204)
__device__ inline int xcd_swz(int bid, int nblk) {
    int q = nblk >> 3, r = nblk & 7;
    int x = bid & 7, p = bid >> 3;
    return (x < r ? x * (q + 1) : r * (q + 1) + (x - r) * q) + p;
}

// ---------------- routing ----------------
__global__ __launch_bounds__(256) void route_kernel(
    const int* __restrict__ idx, const float* __restrict__ scores,
    int* __restrict__ metaA, int* __restrict__ metaB,
    int* __restrict__ slot_token, float* __restrict__ slot_score,
    int* __restrict__ tok_slot, int bmA, int bmB)
{
    __shared__ int counts[NEXP];
    __shared__ int cursor[NEXP];
    int t = threadIdx.x;
    if (t < NEXP) counts[t] = 0;
    __syncthreads();
    for (int i = t; i < NSLOT; i += 256) atomicAdd(&counts[idx[i]], 1);
    __syncthreads();
    if (t == 0) {
        int off = 0, nt = 0;
        for (int e = 0; e < NEXP; e++) {
            cursor[e] = off;
            int c = counts[e];
            for (int s = 0; s < c && nt < MAX_TILES; s += bmA) {
                metaA[1 + nt * 3 + 0] = e;
                metaA[1 + nt * 3 + 1] = off + s;
                metaA[1 + nt * 3 + 2] = min(bmA, c - s);
                nt++;
            }
            off += c;
        }
        metaA[0] = nt;
        off = 0; nt = 0;
        for (int e = 0; e < NEXP; e++) {
            int c = counts[e];
            for (int s = 0; s < c && nt < MAX_TILES; s += bmB) {
                metaB[1 + nt * 3 + 0] = e;
                metaB[1 + nt * 3 + 1] = off + s;
                metaB[1 + nt * 3 + 2] = min(bmB, c - s);
                nt++;
            }
            off += c;
        }
        metaB[0] = nt;
    }
    __syncthreads();
    for (int i = t; i < NSLOT; i += 256) {
        int e = idx[i];
        int pos = atomicAdd(&cursor[e], 1);
        slot_token[pos] = i / TOPK;
        slot_score[pos] = scores[i];
        tok_slot[i] = pos;
    }
}

// ---------------- pre-pass: x fp32 -> bf16 ----------------
__global__ __launch_bounds__(256) void convert_x(
    const float* __restrict__ x, __hip_bfloat16* __restrict__ xb)
{
    int i = blockIdx.x * 256 + threadIdx.x;
    float4 v = reinterpret_cast<const float4*>(x)[i];
    __hip_bfloat16 o[4] = {(__hip_bfloat16)v.x, (__hip_bfloat16)v.y,
                           (__hip_bfloat16)v.z, (__hip_bfloat16)v.w};
    *reinterpret_cast<uint2*>(&xb[(size_t)i * 4]) = *reinterpret_cast<uint2*>(o);
}

// ---------------- pre-pass: per-expert fp32 [R][C] -> bf16 [C][R] ----------------
__global__ __launch_bounds__(256) void transpose_convert(
    const float* __restrict__ in, __hip_bfloat16* __restrict__ out, int R, int C)
{
    __shared__ __hip_bfloat16 t[64][72];
    const size_t base = (size_t)blockIdx.z * R * C;
    const int c0 = blockIdx.x * 64, r0 = blockIdx.y * 64;
    const int tid = threadIdx.x;
    const int rl = tid >> 4, c4 = (tid & 15) * 4;
    #pragma unroll
    for (int j = 0; j < 4; j++) {
        int r = rl + j * 16;
        float4 v = *reinterpret_cast<const float4*>(&in[base + (size_t)(r0 + r) * C + c0 + c4]);
        t[c4 + 0][r] = (__hip_bfloat16)v.x;
        t[c4 + 1][r] = (__hip_bfloat16)v.y;
        t[c4 + 2][r] = (__hip_bfloat16)v.z;
        t[c4 + 3][r] = (__hip_bfloat16)v.w;
    }
    __syncthreads();
    const int nl = tid >> 3, k8 = (tid & 7) * 8;
    #pragma unroll
    for (int j = 0; j < 2; j++) {
        int n = nl + j * 32;
        const uint* p = reinterpret_cast<const uint*>(&t[n][k8]);
        uint4 o = {p[0], p[1], p[2], p[3]};
        *reinterpret_cast<uint4*>(&out[base + (size_t)(c0 + n) * R + r0 + k8]) = o;
    }
}

// ---------------- combine: out[tok] = s0*so[slot0] + s1*so[slot1] ----------------
__global__ __launch_bounds__(256) void combine_kernel(
    const __hip_bfloat16* __restrict__ so, const int* __restrict__ tok_slot,
    const float* __restrict__ slot_score, float* __restrict__ out)
{
    const int tok = blockIdx.x;
    const int c = threadIdx.x * 8;
    const int s0 = tok_slot[tok * 2 + 0], s1 = tok_slot[tok * 2 + 1];
    const float w0 = slot_score[s0], w1 = slot_score[s1];
    bf16x8 v0 = *reinterpret_cast<const bf16x8*>(&so[(size_t)s0 * DMODEL + c]);
    bf16x8 v1 = *reinterpret_cast<const bf16x8*>(&so[(size_t)s1 * DMODEL + c]);
    float res[8];
    #pragma unroll
    for (int j = 0; j < 8; j++) {
        float f0 = __uint_as_float(((uint)(unsigned short)v0[j]) << 16);
        float f1 = __uint_as_float(((uint)(unsigned short)v1[j]) << 16);
        res[j] = w0 * f0 + w1 * f1;
    }
    float4* dst = reinterpret_cast<float4*>(&out[(size_t)tok * DMODEL + c]);
    dst[0] = *reinterpret_cast<float4*>(&res[0]);
    dst[1] = *reinterpret_cast<float4*>(&res[4]);
}

// ---------------- GEMM1 (round-8 proven): BM=256, 128 fused cols, 8 waves ----------------
__global__ __launch_bounds__(512, 2) void moe_gemm1_fast(
    const __hip_bfloat16* __restrict__ xb,
    const __hip_bfloat16* __restrict__ WgT, const __hip_bfloat16* __restrict__ WuT,
    const int* __restrict__ meta, const int* __restrict__ slot_token,
    __hip_bfloat16* __restrict__ h)
{
    const int swz = xcd_swz(blockIdx.x, NTILE_A * NY1);
    const int tile = swz / NY1, yb = swz % NY1;
    if (tile >= meta[0]) return;
    const int e = meta[1 + tile * 3], slot0 = meta[2 + tile * 3], rows = meta[3 + tile * 3];
    const int n0 = yb * 128;

    __shared__ __hip_bfloat16 As[2][256][64];    // 64 KB
    __shared__ __hip_bfloat16 Bgs[2][128][64];   // 32 KB
    __shared__ __hip_bfloat16 Bus[2][128][64];   // 32 KB

    const int tid = threadIdx.x, lane = tid & 63, w = tid >> 6;
    const int wm = w >> 2, wn = w & 3, l15 = lane & 15, lg = lane >> 4;
    const int swb = l15 & 7;

    uint aoff[4], boff[2];
    #pragma unroll
    for (int i = 0; i < 4; i++) {
        int chunk = tid + i * 512;               // [0,2048): row = chunk>>3
        int r = chunk >> 3;
        int rc = r < rows ? r : rows - 1;
        int slot8 = (chunk & 7) ^ (r & 7);
        aoff[i] = (uint)(slot_token[slot0 + rc] * (DMODEL * 2) + slot8 * 16);
    }
    #pragma unroll
    for (int i = 0; i < 2; i++) {
        int chunk = tid + i * 512;               // [0,1024): n = chunk>>3
        int n = chunk >> 3;
        int slot8 = (chunk & 7) ^ (n & 7);
        boff[i] = (uint)((n0 + n) * (DMODEL * 2) + slot8 * 16);
    }
    const char* xbp = (const char*)xb;
    const char* wgp = (const char*)(WgT + (size_t)e * DFF * DMODEL);
    const char* wup = (const char*)(WuT + (size_t)e * DFF * DMODEL);

    f32x4 ag[8][2] = {};
    f32x4 au[8][2] = {};

    auto stage = [&](int kt, int buf) {          // 8 loads per thread
        const int kb = kt * 128;
        char* ab = (char*)As[buf]  + w * 1024;
        char* gb = (char*)Bgs[buf] + w * 1024;
        char* ub = (char*)Bus[buf] + w * 1024;
        #pragma unroll
        for (int i = 0; i < 4; i++) async16(xbp + aoff[i] + kb, ab + i * 8192);
        #pragma unroll
        for (int i = 0; i < 2; i++) {
            async16(wgp + boff[i] + kb, gb + i * 8192);
            async16(wup + boff[i] + kb, ub + i * 8192);
        }
    };

    constexpr int NT = DMODEL / 64;              // 32
    stage(0, 0);
    stage(1, 1);

    for (int kt = 0; kt < NT; ++kt) {
        const int cur = kt & 1;
        if (kt < NT - 1) asm volatile("s_waitcnt vmcnt(8)" ::: "memory");
        else             asm volatile("s_waitcnt vmcnt(0)" ::: "memory");
        __builtin_amdgcn_s_barrier();            // tile kt staged (all waves)

        bf16x8 a[2][8], bg[2][2], bu[2][2];
        #pragma unroll
        for (int kk = 0; kk < 2; kk++) {
            const int cb = ((kk * 4 + lg) ^ swb) * 16;
            #pragma unroll
            for (int mf = 0; mf < 8; mf++)
                a[kk][mf] = *(const bf16x8*)((const char*)&As[cur][wm * 128 + mf * 16 + l15][0] + cb);
            #pragma unroll
            for (int nf = 0; nf < 2; nf++) {
                bg[kk][nf] = *(const bf16x8*)((const char*)&Bgs[cur][wn * 32 + nf * 16 + l15][0] + cb);
                bu[kk][nf] = *(const bf16x8*)((const char*)&Bus[cur][wn * 32 + nf * 16 + l15][0] + cb);
            }
        }
        asm volatile("s_waitcnt lgkmcnt(0)" ::: "memory");
        __builtin_amdgcn_sched_barrier(0);
        __builtin_amdgcn_s_barrier();            // all waves done reading buf[cur]
        if (kt + 2 < NT) stage(kt + 2, cur);     // overwrite freed buffer

        __builtin_amdgcn_s_setprio(1);
        #pragma unroll
        for (int kk = 0; kk < 2; kk++)
            #pragma unroll
            for (int mf = 0; mf < 8; mf++)
                #pragma unroll
                for (int nf = 0; nf < 2; nf++) {
                    ag[mf][nf] = MFMA16(a[kk][mf], bg[kk][nf], ag[mf][nf]);
                    au[mf][nf] = MFMA16(a[kk][mf], bu[kk][nf], au[mf][nf]);
                }
        __builtin_amdgcn_s_setprio(0);
    }

    #pragma unroll
    for (int mf = 0; mf < 8; mf++) {
        #pragma unroll
        for (int j = 0; j < 4; j++) {
            int r = wm * 128 + mf * 16 + lg * 4 + j;
            if (r < rows) {
                size_t hrow = (size_t)(slot0 + r) * DFF + n0 + wn * 32;
                #pragma unroll
                for (int nf = 0; nf < 2; nf++) {
                    float g = ag[mf][nf][j], u = au[mf][nf][j];
                    float hv = g / (1.0f + __expf(-g)) * u;
                    h[hrow + nf * 16 + l15] = (__hip_bfloat16)hv;
                }
            }
        }
    }
}

// ---------------- GEMM2: so[slot] = h@Wd (bf16, atomic-free). BM=128, BN=128 ----------------
__global__ __launch_bounds__(256, 2) void moe_gemm2_fast(
    const __hip_bfloat16* __restrict__ h, const __hip_bfloat16* __restrict__ WdT,
    const int* __restrict__ meta, __hip_bfloat16* __restrict__ so)
{
    const int swz = xcd_swz(blockIdx.x, NTILE_B * NY2);
    const int tile = swz / NY2, yb = swz % NY2;
    if (tile >= meta[0]) return;
    const int e = meta[1 + tile * 3], slot0 = meta[2 + tile * 3], rows = meta[3 + tile * 3];
    const int n0 = yb * 128;

    __shared__ __hip_bfloat16 Ah[2][128][64];   // 32 KB
    __shared__ __hip_bfloat16 Bd[2][128][64];   // 32 KB

    const int tid = threadIdx.x, lane = tid & 63, w = tid >> 6;
    const int wm = w >> 1, wn = w & 1, l15 = lane & 15, lg = lane >> 4;
    const int swb = l15 & 7;

    uint aoff[4], boff[4];
    #pragma unroll
    for (int i = 0; i < 4; i++) {
        int chunk = tid + i * 256;
        int r = chunk >> 3;
        int rc = r < rows ? r : rows - 1;
        int slot8 = (chunk & 7) ^ (r & 7);
        aoff[i] = (uint)((slot0 + rc) * (DFF * 2) + slot8 * 16);
        boff[i] = (uint)((n0 + r) * (DFF * 2) + slot8 * 16);
    }
    const char* hp  = (const char*)h;
    const char* wdp = (const char*)(WdT + (size_t)e * DMODEL * DFF);

    f32x4 acc[4][4] = {};

    auto stage = [&](int kt, int buf) {        // 8 loads per thread
        const int kb = kt * 128;
        char* ab = (char*)Ah[buf] + w * 1024;
        char* bb = (char*)Bd[buf] + w * 1024;
        #pragma unroll
        for (int i = 0; i < 4; i++) {
            async16(hp  + aoff[i] + kb, ab + i * 4096);
            async16(wdp + boff[i] + kb, bb + i * 4096);
        }
    };

    constexpr int NT = DFF / 64;               // 22
    stage(0, 0);
    stage(1, 1);

    for (int kt = 0; kt < NT; ++kt) {
        const int cur = kt & 1;
        if (kt < NT - 1) asm volatile("s_waitcnt vmcnt(8)" ::: "memory");
        else             asm volatile("s_waitcnt vmcnt(0)" ::: "memory");
        __builtin_amdgcn_s_barrier();

        bf16x8 a[2][4], b[2][4];
        #pragma unroll
        for (int kk = 0; kk < 2; kk++) {
            const int cb = ((kk * 4 + lg) ^ swb) * 16;
            #pragma unroll
            for (int mf = 0; mf < 4; mf++) {
                a[kk][mf] = *(const bf16x8*)((const char*)&Ah[cur][wm * 64 + mf * 16 + l15][0] + cb);
                b[kk][mf] = *(const bf16x8*)((const char*)&Bd[cur][wn * 64 + mf * 16 + l15][0] + cb);
            }
        }
        asm volatile("s_waitcnt lgkmcnt(0)" ::: "memory");
        __builtin_amdgcn_sched_barrier(0);
        __builtin_amdgcn_s_barrier();
        if (kt + 2 < NT) stage(kt + 2, cur);

        __builtin_amdgcn_s_setprio(1);
        #pragma unroll
        for (int kk = 0; kk < 2; kk++)
            #pragma unroll
            for (int mf = 0; mf < 4; mf++)
                #pragma unroll
                for (int nf = 0; nf < 4; nf++)
                    acc[mf][nf] = MFMA16(a[kk][mf], b[kk][nf], acc[mf][nf]);
        __builtin_amdgcn_s_setprio(0);
    }

    #pragma unroll
    for (int mf = 0; mf < 4; mf++) {
        #pragma unroll
        for (int j = 0; j < 4; j++) {
            int r = wm * 64 + mf * 16 + lg * 4 + j;
            if (r < rows) {
                size_t orow = (size_t)(slot0 + r) * DMODEL + n0 + wn * 64;
                #pragma unroll
                for (int nf = 0; nf < 4; nf++)
                    so[orow + nf * 16 + l15] = (__hip_bfloat16)acc[mf][nf][j];
            }
        }
    }
}

// ================= fallback (round-2, known-good) =================
__global__ __launch_bounds__(256) void moe_gemm1(
    const float* __restrict__ x, const float* __restrict__ Wg, const float* __restrict__ Wu,
    const int* __restrict__ meta, const int* __restrict__ slot_token,
    __hip_bfloat16* __restrict__ h)
{
    int tile = blockIdx.x;
    if (tile >= meta[0]) return;
    const int e = meta[1 + tile * 3], slot0 = meta[2 + tile * 3], rows = meta[3 + tile * 3];
    const int n0 = blockIdx.y * 64;
    __shared__ __hip_bfloat16 As[64][72];
    __shared__ __hip_bfloat16 Bgs[64][72];
    __shared__ __hip_bfloat16 Bus[64][72];
    const int tid = threadIdx.x, lane = tid & 63, w = tid >> 6;
    const int wm = w >> 1, wn = w & 1, l15 = lane & 15, lg = lane >> 4;
    const float* __restrict__ WgE = Wg + (size_t)e * DMODEL * DFF;
    const float* __restrict__ WuE = Wu + (size_t)e * DMODEL * DFF;
    f32x4 acc_g[2][2] = {};
    f32x4 acc_u[2][2] = {};
    for (int k0 = 0; k0 < DMODEL; k0 += 64) {
        __syncthreads();
        #pragma unroll
        for (int j = 0; j < 4; j++) {
            int linear = tid + j * 256;
            int r = linear >> 4, c4 = (linear & 15) * 4;
            int tok = (r < rows) ? slot_token[slot0 + r] : 0;
            float4 v = *reinterpret_cast<const float4*>(&x[(size_t)tok * DMODEL + k0 + c4]);
            As[r][c4 + 0] = (__hip_bfloat16)v.x; As[r][c4 + 1] = (__hip_bfloat16)v.y;
            As[r][c4 + 2] = (__hip_bfloat16)v.z; As[r][c4 + 3] = (__hip_bfloat16)v.w;
        }
        #pragma unroll
        for (int j = 0; j < 4; j++) {
            int linear = tid + j * 256;
            int k = linear >> 4, n4 = (linear & 15) * 4;
            float4 vg = *reinterpret_cast<const float4*>(&WgE[(size_t)(k0 + k) * DFF + n0 + n4]);
            Bgs[n4 + 0][k] = (__hip_bfloat16)vg.x; Bgs[n4 + 1][k] = (__hip_bfloat16)vg.y;
            Bgs[n4 + 2][k] = (__hip_bfloat16)vg.z; Bgs[n4 + 3][k] = (__hip_bfloat16)vg.w;
            float4 vu = *reinterpret_cast<const float4*>(&WuE[(size_t)(k0 + k) * DFF + n0 + n4]);
            Bus[n4 + 0][k] = (__hip_bfloat16)vu.x; Bus[n4 + 1][k] = (__hip_bfloat16)vu.y;
            Bus[n4 + 2][k] = (__hip_bfloat16)vu.z; Bus[n4 + 3][k] = (__hip_bfloat16)vu.w;
        }
        __syncthreads();
        #pragma unroll
        for (int kk = 0; kk < 2; kk++) {
            bf16x8 a[2], bg[2], bu[2];
            #pragma unroll
            for (int mf = 0; mf < 2; mf++)
                a[mf] = *reinterpret_cast<const bf16x8*>(&As[wm * 32 + mf * 16 + l15][kk * 32 + lg * 8]);
            #pragma unroll
            for (int nf = 0; nf < 2; nf++) {
                bg[nf] = *reinterpret_cast<const bf16x8*>(&Bgs[wn * 32 + nf * 16 + l15][kk * 32 + lg * 8]);
                bu[nf] = *reinterpret_cast<const bf16x8*>(&Bus[wn * 32 + nf * 16 + l15][kk * 32 + lg * 8]);
            }
            #pragma unroll
            for (int mf = 0; mf < 2; mf++)
                #pragma unroll
                for (int nf = 0; nf < 2; nf++) {
                    acc_g[mf][nf] = MFMA16(a[mf], bg[nf], acc_g[mf][nf]);
                    acc_u[mf][nf] = MFMA16(a[mf], bu[nf], acc_u[mf][nf]);
                }
        }
    }
    #pragma unroll
    for (int mf = 0; mf < 2; mf++)
        #pragma unroll
        for (int nf = 0; nf < 2; nf++)
            #pragma unroll
            for (int j = 0; j < 4; j++) {
                int r = wm * 32 + mf * 16 + lg * 4 + j;
                int c = wn * 32 + nf * 16 + l15;
                if (r < rows) {
                    float g = acc_g[mf][nf][j], u = acc_u[mf][nf][j];
                    h[(size_t)(slot0 + r) * DFF + n0 + c] = (__hip_bfloat16)(g / (1.0f + __expf(-g)) * u);
                }
            }
}

__global__ __launch_bounds__(256) void moe_gemm2(
    const __hip_bfloat16* __restrict__ h, const float* __restrict__ Wd,
    const int* __restrict__ meta, const int* __restrict__ slot_token,
    const float* __restrict__ slot_score, float* __restrict__ out)
{
    int tile = blockIdx.x;
    if (tile >= meta[0]) return;
    const int e = meta[1 + tile * 3], slot0 = meta[2 + tile * 3], rows = meta[3 + tile * 3];
    const int n0 = blockIdx.y * 64;
    __shared__ __hip_bfloat16 As[64][72];
    __shared__ __hip_bfloat16 Bs[64][72];
    const int tid = threadIdx.x, lane = tid & 63, w = tid >> 6;
    const int wm = w >> 1, wn = w & 1, l15 = lane & 15, lg = lane >> 4;
    const float* __restrict__ WdE = Wd + (size_t)e * DFF * DMODEL;
    f32x4 acc[2][2] = {};
    for (int k0 = 0; k0 < DFF; k0 += 64) {
        __syncthreads();
        #pragma unroll
        for (int j = 0; j < 2; j++) {
            int linear = tid + j * 256;
            int r = linear >> 3, c8 = (linear & 7) * 8;
            bf16x8 v = *reinterpret_cast<const bf16x8*>(&h[(size_t)(slot0 + r) * DFF + k0 + c8]);
            *reinterpret_cast<bf16x8*>(&As[r][c8]) = v;
        }
        #pragma unroll
        for (int j = 0; j < 4; j++) {
            int linear = tid + j * 256;
            int k = linear >> 4, n4 = (linear & 15) * 4;
            float4 v = *reinterpret_cast<const float4*>(&WdE[(size_t)(k0 + k) * DMODEL + n0 + n4]);
            Bs[n4 + 0][k] = (__hip_bfloat16)v.x; Bs[n4 + 1][k] = (__hip_bfloat16)v.y;
            Bs[n4 + 2][k] = (__hip_bfloat16)v.z; Bs[n4 + 3][k] = (__hip_bfloat16)v.w;
        }
        __syncthreads();
        #pragma unroll
        for (int kk = 0; kk < 2; kk++) {
            bf16x8 a[2], b[2];
            #pragma unroll
            for (int mf = 0; mf < 2; mf++)
                a[mf] = *reinterpret_cast<const bf16x8*>(&As[wm * 32 + mf * 16 + l15][kk * 32 + lg * 8]);
            #pragma unroll
            for (int nf = 0; nf < 2; nf++)
                b[nf] = *reinterpret_cast<const bf16x8*>(&Bs[wn * 32 + nf * 16 + l15][kk * 32 + lg * 8]);
            #pragma unroll
            for (int mf = 0; mf < 2; mf++)
                #pragma unroll
                for (int nf = 0; nf < 2; nf++)
                    acc[mf][nf] = MFMA16(a[mf], b[nf], acc[mf][nf]);
        }
    }
    #pragma unroll
    for (int mf = 0; mf < 2; mf++)
        #pragma unroll
        for (int nf = 0; nf < 2; nf++)
            #pragma unroll
            for (int j = 0; j < 4; j++) {
                int r = wm * 32 + mf * 16 + lg * 4 + j;
                int c = wn * 32 + nf * 16 + l15;
                if (r < rows) {
                    int slot = slot0 + r;
                    atomicAdd(&out[(size_t)slot_token[slot] * DMODEL + n0 + c],
                              acc[mf][nf][j] * slot_score[slot]);
                }
            }
}

extern "C" void kernel_launch(void* const* d_in, const int* in_sizes, int n_in,
                              void* d_out, int out_size, void* d_ws, size_t ws_size,
                              hipStream_t stream) {
    const float* x      = (const float*)d_in[0];
    const int*   idx    = (const int*)d_in[1];
    const float* scores = (const float*)d_in[2];
    const float* Wg     = (const float*)d_in[3];
    const float* Wu     = (const float*)d_in[4];
    const float* Wd     = (const float*)d_in[5];
    float* out = (float*)d_out;

    char* ws = (char*)d_ws;
    int*   metaA      = (int*)ws;
    int*   metaB      = (int*)(ws + 4096);
    int*   slot_token = (int*)(ws + 8192);
    float* slot_score = (float*)(ws + 8192 + 40960);
    int*   tok_slot   = (int*)(ws + 8192 + 81920);

    const size_t XB_OFF = (size_t)1 << 20;
    const size_t HB_OFF = (size_t)20 << 20;
    const size_t WG_OFF = (size_t)44 << 20;   // WgT during gemm1; slot_out after
    const size_t WU_OFF = (size_t)92 << 20;
    const size_t WD_OFF = (size_t)140 << 20;
    const size_t NEED   = (size_t)187 << 20;
    const bool fast = ws_size >= NEED;

    route_kernel<<<1, 256, 0, stream>>>(idx, scores, metaA, metaB, slot_token, slot_score,
                                        tok_slot, fast ? 256 : 64, fast ? 128 : 64);

    if (fast) {
        __hip_bfloat16* xb  = (__hip_bfloat16*)(ws + XB_OFF);
        __hip_bfloat16* hb  = (__hip_bfloat16*)(ws + HB_OFF);
        __hip_bfloat16* WgT = (__hip_bfloat16*)(ws + WG_OFF);
        __hip_bfloat16* WuT = (__hip_bfloat16*)(ws + WU_OFF);
        __hip_bfloat16* WdT = (__hip_bfloat16*)(ws + WD_OFF);
        __hip_bfloat16* sot = (__hip_bfloat16*)(ws + WG_OFF);  // reuse WgT after gemm1

        dim3 td(DMODEL / 64, DFF / 64, NEXP);
        transpose_convert<<<td, 256, 0, stream>>>(Wd, WdT, DFF, DMODEL);
        dim3 tg(DFF / 64, DMODEL / 64, NEXP);
        transpose_convert<<<tg, 256, 0, stream>>>(Wg, WgT, DMODEL, DFF);
        transpose_convert<<<tg, 256, 0, stream>>>(Wu, WuT, DMODEL, DFF);
        convert_x<<<(NTOK * DMODEL / 4) / 256, 256, 0, stream>>>(x, xb);

        moe_gemm1_fast<<<NTILE_A * NY1, 512, 0, stream>>>(xb, WgT, WuT, metaA, slot_token, hb);
        moe_gemm2_fast<<<NTILE_B * NY2, 256, 0, stream>>>(hb, WdT, metaB, sot);
        combine_kernel<<<NTOK, 256, 0, stream>>>(sot, tok_slot, slot_score, out);
    } else {
        __hip_bfloat16* hb = (__hip_bfloat16*)(ws + HB_OFF);
        hipMemsetAsync(d_out, 0, (size_t)NTOK * DMODEL * sizeof(float), stream);
        dim3 g1(NSLOT / 64 + NEXP, DFF / 64);
        moe_gemm1<<<g1, 256, 0, stream>>>(x, Wg, Wu, metaA, slot_token, hb);
        dim3 g2(NSLOT / 64 + NEXP, DMODEL / 64);
        moe_gemm2<<<g2, 256, 0, stream>>>(hb, Wd, metaB, slot_token, slot_score, out);
    }
}